// Round 2
// baseline (116.089 us; speedup 1.0000x reference)
//
#include <hip/hip_runtime.h>

// out[b,o] = sum_k w[idx[b],o,k] * x[b,k];  B=2048, C=64, IN=OUT=512.
//
// r8 == r7 resubmitted: round-1 bench died with "MI355X container failed
// twice" (infra acquire/run failure — no counters, no pass/fail verdict).
// Kernel re-audited for hang/fault paths (barrier uniformity, bounds, vmcnt
// discipline) — none found; resubmitting unchanged to get a measurement.
//
// r7 design: r6 (contiguous 32KB staging) was still memory-IDLE bound: each
// of 2048 blocks ran a serial {stage 32KB -> full vmcnt drain -> tiny
// compute (8 MFMA/wave) -> 2 more full-drain barriers}, so per CU the VMEM
// queue was empty ~75% of the time (measured 1.3 TB/s vs 6.3 achievable;
// traffic itself was already minimal). Restructure for continuous W stream:
//   * grid 512 = 64 classes x 8 row-groups; block owns 4 consecutive 16-row
//     tiles = one contiguous 128KB W stream.
//   * Wl double-buffered (2 x 32KB): stage(t+1) issued right after the
//     tile-start __syncthreads, so 8KB/wave of global_load_lds is in flight
//     across all of compute(t).
//   * K-reduce barriers are lgkmcnt-only raw s_barriers (NO vmcnt drain) so
//     they don't drain the in-flight stage. Only the tile-start __syncthreads
//     drains vmcnt (that is what guarantees stage(t) landed).
//   * idx scan + list build once per block (amortized over 4 tiles).
//   * red shrunk to rounds-of-2-groups (6KB): LDS = 75.8KB -> 2 blocks/CU.
//   * XCD-bijective swizzle groups the 8 blocks of a class on one XCD
//     (shared x-row gathers hit the same L2).  512 % 8 == 0 -> bijective.

constexpr int Bsz  = 2048;
constexpr int Ccnt = 64;
constexpr int INF  = 512;
constexpr int OUTF = 512;
constexpr int THREADS = 256;   // 4 waves = 4 K-quarters
constexpr int OT  = 16;        // out rows per staged tile
constexpr int TPB = 4;         // consecutive tiles per block
constexpr int NBLK = Ccnt * (OUTF / (OT * TPB));   // 512

typedef __attribute__((ext_vector_type(8))) short bf16x8;
typedef __attribute__((ext_vector_type(4))) float f32x4;

#if __has_builtin(__builtin_amdgcn_cvt_pk_bf16_f32)
typedef __attribute__((ext_vector_type(2))) __bf16 bf16x2_t;
__device__ __forceinline__ int cvt2i(float a, float b) {
    union { bf16x2_t v; int i; } u;
    u.v = __builtin_amdgcn_cvt_pk_bf16_f32(a, b);
    return u.i;
}
#else
__device__ __forceinline__ unsigned f2bf(float f) {
    union { float f; unsigned u; } v; v.f = f;
    return (v.u + 0x7FFFu + ((v.u >> 16) & 1u)) >> 16;   // RNE
}
__device__ __forceinline__ int cvt2i(float a, float b) {
    return (int)(f2bf(a) | (f2bf(b) << 16));
}
#endif

__device__ __forceinline__ bf16x8 cvt8(float4 a, float4 b) {
    union { bf16x8 v; int i[4]; } u;
    u.i[0] = cvt2i(a.x, a.y);
    u.i[1] = cvt2i(a.z, a.w);
    u.i[2] = cvt2i(b.x, b.y);
    u.i[3] = cvt2i(b.z, b.w);
    return u.v;
}

// async 16B/lane global -> LDS (dest = wave-uniform base + lane*16)
__device__ __forceinline__ void gld_lds16(const float* g, float* l) {
    __builtin_amdgcn_global_load_lds(
        (const __attribute__((address_space(1))) float*)g,
        (__attribute__((address_space(3))) float*)l, 16, 0, 0);
}

// workgroup barrier that does NOT drain vmcnt (keeps async stage in flight)
__device__ __forceinline__ void barrier_lgkm() {
    asm volatile("s_waitcnt lgkmcnt(0)" ::: "memory");
    __builtin_amdgcn_s_barrier();
    asm volatile("" ::: "memory");
}

// stage one 16x512 f32 tile (contiguous 32KB) into LDS, 8 x 1KB insts/wave.
// Element (r,k) lands at dst[r*512 + ((k>>2) ^ (r&7))*4 + (k&3)]  (16B-granule
// XOR swizzle applied on the SOURCE side within 128B lines -> coalescing
// identical to a linear copy; reads de-swizzle with the same XOR).
__device__ __forceinline__ void stage_tile(const float* wt, float* dst,
                                           int wave, int lane) {
#pragma unroll
    for (int i = 0; i < 8; ++i) {
        const int inst = wave * 8 + i;
        const int r = inst >> 1;
        const int h = inst & 1;
        const int p = r & 7;
        const float* src = wt + (size_t)r * INF + (h * 64 + (lane ^ p)) * 4;
        gld_lds16(src, dst + inst * 256);
    }
}

__global__ __launch_bounds__(THREADS, 2)
void switching_linear_kernel(const float* __restrict__ x,
                             const int* __restrict__ idx,
                             const float* __restrict__ w,
                             float* __restrict__ out) {
    __shared__ float Wl[2][OT * INF];       // 64 KB double-buffered W tile
    __shared__ unsigned short list[Bsz];    // 4 KB
    __shared__ int ls_n;
    __shared__ float red[2][3][4][64];      // 6 KB (rounds of 2 groups)

    const int tid  = threadIdx.x;
    const int wave = tid >> 6;
    const int lane = tid & 63;

    // XCD-bijective swizzle: the 8 blocks of a class land on one XCD
    const int bid   = ((int)blockIdx.x & 7) * (NBLK / 8) + ((int)blockIdx.x >> 3);
    const int c     = bid >> 3;                 // class
    const int obase = (bid & 7) * (OT * TPB);   // first of 64 contiguous rows

    if (tid == 0) ls_n = 0;
    __syncthreads();   // nothing in flight yet

    const float* wc = w + (size_t)c * OUTF * INF + (size_t)obase * INF;

    // prologue: tile 0 staging in flight while we scan idx
    stage_tile(wc, Wl[0], wave, lane);

    int my[8];
#pragma unroll
    for (int i = 0; i < 8; ++i) my[i] = idx[tid + i * THREADS];
#pragma unroll
    for (int i = 0; i < 8; ++i)
        if (my[i] == c) list[atomicAdd(&ls_n, 1)] = (unsigned short)(tid + i * THREADS);

    const int mrow = lane & 15;   // A row / C col
    const int quad = lane >> 4;   // k segment / C row group
    const int k0   = wave * (INF / 4);
    const int p    = mrow & 7;

    int n = 0;

    for (int ot = 0; ot < TPB; ++ot) {
        __syncthreads();            // stage(ot) landed (+ list complete on ot==0)
        if (ot == 0) {
            n = ls_n;
            if (n == 0) return;     // uniform; nothing left in flight after drain
        }
        if (ot + 1 < TPB)           // issue next tile EARLY -> overlaps compute
            stage_tile(wc + (size_t)((ot + 1) * OT) * INF, Wl[(ot + 1) & 1],
                       wave, lane);

        const float* Wb = Wl[ot & 1];
        const int o0 = obase + ot * OT;

        // A-fragments for this tile (reused across all sample groups)
        bf16x8 wf[4];
#pragma unroll
        for (int t = 0; t < 4; ++t) {
            const int gb = (k0 >> 2) + t * 8 + quad * 2;   // granule in row
            float4 a0 = *(const float4*)&Wb[mrow * INF + ((gb)     ^ p) * 4];
            float4 a1 = *(const float4*)&Wb[mrow * INF + ((gb + 1) ^ p) * 4];
            wf[t] = cvt8(a0, a1);
        }

        for (int s0 = 0; s0 < n; s0 += 64) {
            const int rem = n - s0;
            const int ng  = rem >= 64 ? 4 : (rem + 15) >> 4;

            f32x4 acc[4];
#pragma unroll
            for (int g = 0; g < 4; ++g) acc[g] = (f32x4){0.f, 0.f, 0.f, 0.f};

            // static g indexing everywhere (no scratch); invalid lanes clamp
            // to a valid sample — their C columns are never stored.
#pragma unroll
            for (int g = 0; g < 4; ++g) {
                if (g < ng) {
                    const int s  = s0 + g * 16 + mrow;
                    const int sc = s < n ? s : n - 1;
                    const float* bp = x + (size_t)list[sc] * INF + k0 + quad * 8;
#pragma unroll
                    for (int i = 0; i < 4; ++i) {
                        float4 b0 = *(const float4*)(bp + i * 32);
                        float4 b1 = *(const float4*)(bp + i * 32 + 4);
                        acc[g] = __builtin_amdgcn_mfma_f32_16x16x32_bf16(
                                     wf[i], cvt8(b0, b1), acc[g], 0, 0, 0);
                    }
                }
            }

            // K-reduce across 4 waves, rounds of 2 groups (fixed order ->
            // deterministic). lgkm-only barriers keep stage(ot+1) in flight.
#pragma unroll
            for (int r0 = 0; r0 < 4; r0 += 2) {
                if (r0 < ng) {                       // uniform across block
                    if (wave != 0) {
#pragma unroll
                        for (int g = 0; g < 2; ++g) {
                            if (r0 + g < ng) {
#pragma unroll
                                for (int j = 0; j < 4; ++j)
                                    red[g][wave - 1][j][lane] = acc[r0 + g][j];
                            }
                        }
                    }
                    barrier_lgkm();
                    if (wave == 0) {
#pragma unroll
                        for (int g = 0; g < 2; ++g) {
                            if (r0 + g < ng) {
                                const int s = s0 + (r0 + g) * 16 + mrow;
                                if (s < n) {
                                    f32x4 a = acc[r0 + g];
#pragma unroll
                                    for (int wv2 = 0; wv2 < 3; ++wv2)
#pragma unroll
                                        for (int j = 0; j < 4; ++j)
                                            a[j] += red[g][wv2][j][lane];
                                    float* dst = out + (size_t)list[s] * OUTF
                                                     + o0 + quad * 4;
                                    *(float4*)dst = make_float4(a[0], a[1],
                                                                a[2], a[3]);
                                }
                            }
                        }
                    }
                    barrier_lgkm();                  // red reusable next round
                }
            }
        }
    }
}

extern "C" void kernel_launch(void* const* d_in, const int* in_sizes, int n_in,
                              void* d_out, int out_size, void* d_ws, size_t ws_size,
                              hipStream_t stream) {
    const float* x   = (const float*)d_in[0];
    const int*   idx = (const int*)d_in[1];
    const float* w   = (const float*)d_in[2];
    float* out = (float*)d_out;

    switching_linear_kernel<<<dim3(NBLK), dim3(THREADS), 0, stream>>>(x, idx, w, out);
}

// Round 3
// 105.294 us; speedup vs baseline: 1.1025x; 1.1025x over previous
//
#include <hip/hip_runtime.h>

// out[b,o] = sum_k w[idx[b],o,k] * x[b,k];  B=2048, C=64, IN=OUT=512.
//
// r9: r7's double-buffered stage never overlapped: vmcnt is an in-order
// FIFO, and the per-group x-gathers (vmem->VGPR, issued AFTER the 8
// global_load_lds staging insts) forced every xf wait to first drain the
// staging loads. Kernel sat at ~29-31us (~2.5 TB/s effective) in both r6
// and r7. Fix: make the tile loop vmem-consumer-free.
//   * x fragments are tile-invariant -> preload chunk-0 xf (16 x bf16x8,
//     64 VGPR) ONCE in the prologue; tile loop = stage(ot+1) issue +
//     wf ds_read (lgkm) + MFMA from regs + LDS K-reduce (lgkm barriers).
//     Only the end-of-tile __syncthreads drains vmcnt -> stage(ot+1) has
//     the full compute+reduce window in flight.
//   * x no longer re-gathered 4x (once per block instead of once per tile).
//   * n>64 chunks: rare (P ~ 1e-6) slow path with in-loop gathers
//     (correctness only; drains staging, perf irrelevant).
//   * rest = r7: grid 512 (64 classes x 8 row-groups), contiguous 128KB
//     W stream per block, 2x32KB Wl, source-side 16B-granule XOR swizzle,
//     XCD-bijective block swizzle, LDS 75.8KB -> 2 blocks/CU.

constexpr int Bsz  = 2048;
constexpr int Ccnt = 64;
constexpr int INF  = 512;
constexpr int OUTF = 512;
constexpr int THREADS = 256;   // 4 waves = 4 K-quarters
constexpr int OT  = 16;        // out rows per staged tile
constexpr int TPB = 4;         // consecutive tiles per block
constexpr int NBLK = Ccnt * (OUTF / (OT * TPB));   // 512

typedef __attribute__((ext_vector_type(8))) short bf16x8;
typedef __attribute__((ext_vector_type(4))) float f32x4;

#if __has_builtin(__builtin_amdgcn_cvt_pk_bf16_f32)
typedef __attribute__((ext_vector_type(2))) __bf16 bf16x2_t;
__device__ __forceinline__ int cvt2i(float a, float b) {
    union { bf16x2_t v; int i; } u;
    u.v = __builtin_amdgcn_cvt_pk_bf16_f32(a, b);
    return u.i;
}
#else
__device__ __forceinline__ unsigned f2bf(float f) {
    union { float f; unsigned u; } v; v.f = f;
    return (v.u + 0x7FFFu + ((v.u >> 16) & 1u)) >> 16;   // RNE
}
__device__ __forceinline__ int cvt2i(float a, float b) {
    return (int)(f2bf(a) | (f2bf(b) << 16));
}
#endif

__device__ __forceinline__ bf16x8 cvt8(float4 a, float4 b) {
    union { bf16x8 v; int i[4]; } u;
    u.i[0] = cvt2i(a.x, a.y);
    u.i[1] = cvt2i(a.z, a.w);
    u.i[2] = cvt2i(b.x, b.y);
    u.i[3] = cvt2i(b.z, b.w);
    return u.v;
}

// async 16B/lane global -> LDS (dest = wave-uniform base + lane*16)
__device__ __forceinline__ void gld_lds16(const float* g, float* l) {
    __builtin_amdgcn_global_load_lds(
        (const __attribute__((address_space(1))) float*)g,
        (__attribute__((address_space(3))) float*)l, 16, 0, 0);
}

// workgroup barrier that does NOT drain vmcnt (keeps async stage in flight)
__device__ __forceinline__ void barrier_lgkm() {
    asm volatile("s_waitcnt lgkmcnt(0)" ::: "memory");
    __builtin_amdgcn_s_barrier();
    asm volatile("" ::: "memory");
}

// stage one 16x512 f32 tile (contiguous 32KB) into LDS, 8 x 1KB insts/wave.
// Element (r,k) lands at dst[r*512 + (((k>>2) ^ (r&7)))*4 + (k&3)] (16B-
// granule XOR swizzle applied on the SOURCE side within 128B lines ->
// coalescing identical to a linear copy; reads de-swizzle with same XOR).
__device__ __forceinline__ void stage_tile(const float* wt, float* dst,
                                           int wave, int lane) {
#pragma unroll
    for (int i = 0; i < 8; ++i) {
        const int inst = wave * 8 + i;
        const int r = inst >> 1;
        const int h = inst & 1;
        const int p = r & 7;
        const float* src = wt + (size_t)r * INF + (h * 64 + (lane ^ p)) * 4;
        gld_lds16(src, dst + inst * 256);
    }
}

// cross-wave K-reduce + store, rounds of 2 groups (fixed order ->
// deterministic). lgkm-only barriers: never drains in-flight staging.
__device__ __forceinline__ void kreduce_store(
        const f32x4* acc, int ng, int s0, int n, int o0,
        int wave, int lane, int mrow, int quad,
        const unsigned short* list, float (*red)[3][4][64],
        float* __restrict__ out) {
#pragma unroll
    for (int r0 = 0; r0 < 4; r0 += 2) {
        if (r0 < ng) {                       // uniform across block
            if (wave != 0) {
#pragma unroll
                for (int g = 0; g < 2; ++g) {
                    if (r0 + g < ng) {
#pragma unroll
                        for (int j = 0; j < 4; ++j)
                            red[g][wave - 1][j][lane] = acc[r0 + g][j];
                    }
                }
            }
            barrier_lgkm();
            if (wave == 0) {
#pragma unroll
                for (int g = 0; g < 2; ++g) {
                    if (r0 + g < ng) {
                        const int s = s0 + (r0 + g) * 16 + mrow;
                        if (s < n) {
                            f32x4 a = acc[r0 + g];
#pragma unroll
                            for (int wv2 = 0; wv2 < 3; ++wv2)
#pragma unroll
                                for (int j = 0; j < 4; ++j)
                                    a[j] += red[g][wv2][j][lane];
                            float* dst = out + (size_t)list[s] * OUTF
                                             + o0 + quad * 4;
                            *(float4*)dst = make_float4(a[0], a[1], a[2], a[3]);
                        }
                    }
                }
            }
            barrier_lgkm();                  // red reusable next round
        }
    }
}

__global__ __launch_bounds__(THREADS, 2)
void switching_linear_kernel(const float* __restrict__ x,
                             const int* __restrict__ idx,
                             const float* __restrict__ w,
                             float* __restrict__ out) {
    __shared__ float Wl[2][OT * INF];       // 64 KB double-buffered W tile
    __shared__ unsigned short list[Bsz];    // 4 KB
    __shared__ int ls_n;
    __shared__ float red[2][3][4][64];      // 6 KB (rounds of 2 groups)

    const int tid  = threadIdx.x;
    const int wave = tid >> 6;
    const int lane = tid & 63;

    // XCD-bijective swizzle: the 8 blocks of a class land on one XCD
    const int bid   = ((int)blockIdx.x & 7) * (NBLK / 8) + ((int)blockIdx.x >> 3);
    const int c     = bid >> 3;                 // class
    const int obase = (bid & 7) * (OT * TPB);   // first of 64 contiguous rows

    if (tid == 0) ls_n = 0;
    __syncthreads();   // nothing in flight yet

    // ---- idx scan + list build ----
    int my[8];
#pragma unroll
    for (int i = 0; i < 8; ++i) my[i] = idx[tid + i * THREADS];
#pragma unroll
    for (int i = 0; i < 8; ++i)
        if (my[i] == c) list[atomicAdd(&ls_n, 1)] = (unsigned short)(tid + i * THREADS);

    __syncthreads();   // list complete (drains idx loads; nothing else)
    const int n = ls_n;
    if (n == 0) return;             // uniform; nothing in flight

    const int mrow = lane & 15;   // A row / C col
    const int quad = lane >> 4;   // k segment / C row group
    const int k0   = wave * (INF / 4);
    const int p    = mrow & 7;
    const float* wc = w + (size_t)c * OUTF * INF + (size_t)obase * INF;

    // ---- prologue: stage(0) in flight while we gather+convert chunk-0 x ----
    stage_tile(wc, Wl[0], wave, lane);

    const int ng0 = (n >= 64) ? 4 : ((n + 15) >> 4);
    bf16x8 xf[4][4];                // chunk-0 x fragments, reused by all tiles
#pragma unroll
    for (int g = 0; g < 4; ++g) {
        if (g < ng0) {
            const int s  = g * 16 + mrow;
            const int sc = s < n ? s : n - 1;
            const float* bp = x + (size_t)list[sc] * INF + k0 + quad * 8;
#pragma unroll
            for (int i = 0; i < 4; ++i) {
                float4 b0 = *(const float4*)(bp + i * 32);
                float4 b1 = *(const float4*)(bp + i * 32 + 4);
                xf[g][i] = cvt8(b0, b1);
            }
        }
    }

    __syncthreads();   // stage(0) landed; xf complete

    for (int ot = 0; ot < TPB; ++ot) {
        if (ot + 1 < TPB)           // issue next tile EARLY; nothing in the
            stage_tile(wc + (size_t)((ot + 1) * OT) * INF,   // tile body waits
                       Wl[(ot + 1) & 1], wave, lane);        // on vmcnt

        const float* Wb = Wl[ot & 1];
        const int o0 = obase + ot * OT;

        // A-fragments for this tile (LDS -> regs, lgkm domain only)
        bf16x8 wf[4];
#pragma unroll
        for (int t = 0; t < 4; ++t) {
            const int gb = (k0 >> 2) + t * 8 + quad * 2;   // granule in row
            float4 a0 = *(const float4*)&Wb[mrow * INF + ((gb)     ^ p) * 4];
            float4 a1 = *(const float4*)&Wb[mrow * INF + ((gb + 1) ^ p) * 4];
            wf[t] = cvt8(a0, a1);
        }

        // ---- chunk 0: pure register MFMA (no vmem -> stage stays in flight)
        {
            f32x4 acc[4];
#pragma unroll
            for (int g = 0; g < 4; ++g) acc[g] = (f32x4){0.f, 0.f, 0.f, 0.f};
#pragma unroll
            for (int g = 0; g < 4; ++g) {
                if (g < ng0) {
#pragma unroll
                    for (int i = 0; i < 4; ++i)
                        acc[g] = __builtin_amdgcn_mfma_f32_16x16x32_bf16(
                                     wf[i], xf[g][i], acc[g], 0, 0, 0);
                }
            }
            kreduce_store(acc, ng0, 0, n, o0, wave, lane, mrow, quad,
                          list, red, out);
        }

        // ---- rare slow path: chunks beyond 64 samples (gathers in-loop) ----
        for (int s0 = 64; s0 < n; s0 += 64) {
            const int rem = n - s0;
            const int ng  = rem >= 64 ? 4 : (rem + 15) >> 4;

            f32x4 acc[4];
#pragma unroll
            for (int g = 0; g < 4; ++g) acc[g] = (f32x4){0.f, 0.f, 0.f, 0.f};
#pragma unroll
            for (int g = 0; g < 4; ++g) {
                if (g < ng) {
                    const int s  = s0 + g * 16 + mrow;
                    const int sc = s < n ? s : n - 1;
                    const float* bp = x + (size_t)list[sc] * INF + k0 + quad * 8;
#pragma unroll
                    for (int i = 0; i < 4; ++i) {
                        float4 b0 = *(const float4*)(bp + i * 32);
                        float4 b1 = *(const float4*)(bp + i * 32 + 4);
                        acc[g] = __builtin_amdgcn_mfma_f32_16x16x32_bf16(
                                     wf[i], cvt8(b0, b1), acc[g], 0, 0, 0);
                    }
                }
            }
            kreduce_store(acc, ng, s0, n, o0, wave, lane, mrow, quad,
                          list, red, out);
        }

        if (ot + 1 < TPB)
            __syncthreads();   // drains stage(ot+1); Wl[ot&1] reusable
    }
}

extern "C" void kernel_launch(void* const* d_in, const int* in_sizes, int n_in,
                              void* d_out, int out_size, void* d_ws, size_t ws_size,
                              hipStream_t stream) {
    const float* x   = (const float*)d_in[0];
    const int*   idx = (const int*)d_in[1];
    const float* w   = (const float*)d_in[2];
    float* out = (float*)d_out;

    switching_linear_kernel<<<dim3(NBLK), dim3(THREADS), 0, stream>>>(x, idx, w, out);
}

// Round 4
// 105.174 us; speedup vs baseline: 1.1038x; 1.0011x over previous
//
#include <hip/hip_runtime.h>

// out[b,o] = sum_k w[idx[b],o,k] * x[b,k];  B=2048, C=64, IN=OUT=512.
//
// r10: r9 (-11us, confirmed vmcnt-FIFO theory) still FULL-drains stage(t+1)
// at every end-of-tile __syncthreads (vmcnt(0)): per tile = compute 0.4us +
// drain-wait 2.3us, with an empty VMEM queue between drain and next issue.
// Replace with counted waits (T4): each wave stages exactly 8
// global_load_lds per tile, so `s_waitcnt vmcnt(8)` + raw s_barrier
// guarantees stage(t) landed while stage(t+1) keeps flying ACROSS the
// barrier. Cadence:
//   stage(0)->B0; x-gather+cvt (waits drain stage(0) - needed for tile0
//   anyway); stage(1)->B1; vm8+bar;
//   tile t: wf ds_read + MFMA + reduce(lgkm bars) -> stage(t+2)->B[t&1]
//           -> vm8+bar (vm0 for the last stage).
// Buffer safety: stage(t+2) reuses B[t&1] only after kreduce's final
// barrier (all waves past their wf reads). sched_barrier(0) after each
// inline waitcnt (rule #18). Rest = r9: grid 512, 128KB W stream/block,
// source-side XOR swizzle, XCD-bijective swizzle, xf preloaded in regs,
// rare n>64 slow path, LDS 75.8KB -> 2 blocks/CU.

constexpr int Bsz  = 2048;
constexpr int Ccnt = 64;
constexpr int INF  = 512;
constexpr int OUTF = 512;
constexpr int THREADS = 256;   // 4 waves = 4 K-quarters
constexpr int OT  = 16;        // out rows per staged tile
constexpr int TPB = 4;         // consecutive tiles per block
constexpr int NBLK = Ccnt * (OUTF / (OT * TPB));   // 512

typedef __attribute__((ext_vector_type(8))) short bf16x8;
typedef __attribute__((ext_vector_type(4))) float f32x4;

#if __has_builtin(__builtin_amdgcn_cvt_pk_bf16_f32)
typedef __attribute__((ext_vector_type(2))) __bf16 bf16x2_t;
__device__ __forceinline__ int cvt2i(float a, float b) {
    union { bf16x2_t v; int i; } u;
    u.v = __builtin_amdgcn_cvt_pk_bf16_f32(a, b);
    return u.i;
}
#else
__device__ __forceinline__ unsigned f2bf(float f) {
    union { float f; unsigned u; } v; v.f = f;
    return (v.u + 0x7FFFu + ((v.u >> 16) & 1u)) >> 16;   // RNE
}
__device__ __forceinline__ int cvt2i(float a, float b) {
    return (int)(f2bf(a) | (f2bf(b) << 16));
}
#endif

__device__ __forceinline__ bf16x8 cvt8(float4 a, float4 b) {
    union { bf16x8 v; int i[4]; } u;
    u.i[0] = cvt2i(a.x, a.y);
    u.i[1] = cvt2i(a.z, a.w);
    u.i[2] = cvt2i(b.x, b.y);
    u.i[3] = cvt2i(b.z, b.w);
    return u.v;
}

// async 16B/lane global -> LDS (dest = wave-uniform base + lane*16)
__device__ __forceinline__ void gld_lds16(const float* g, float* l) {
    __builtin_amdgcn_global_load_lds(
        (const __attribute__((address_space(1))) float*)g,
        (__attribute__((address_space(3))) float*)l, 16, 0, 0);
}

// workgroup barrier that does NOT touch vmcnt (keeps staging in flight)
__device__ __forceinline__ void barrier_lgkm() {
    asm volatile("s_waitcnt lgkmcnt(0)" ::: "memory");
    __builtin_amdgcn_s_barrier();
    asm volatile("" ::: "memory");
}

// counted-vmcnt barriers: own stage portion (8 ops) landed, next keeps flying
__device__ __forceinline__ void vm8_barrier() {
    asm volatile("s_waitcnt vmcnt(8)" ::: "memory");
    __builtin_amdgcn_sched_barrier(0);
    __builtin_amdgcn_s_barrier();
    asm volatile("" ::: "memory");
}
__device__ __forceinline__ void vm0_barrier() {
    asm volatile("s_waitcnt vmcnt(0)" ::: "memory");
    __builtin_amdgcn_sched_barrier(0);
    __builtin_amdgcn_s_barrier();
    asm volatile("" ::: "memory");
}

// stage one 16x512 f32 tile (contiguous 32KB) into LDS, 8 x 1KB insts/wave.
// Element (r,k) lands at dst[r*512 + (((k>>2) ^ (r&7)))*4 + (k&3)] (16B-
// granule XOR swizzle applied on the SOURCE side within 128B lines ->
// coalescing identical to a linear copy; reads de-swizzle with same XOR).
__device__ __forceinline__ void stage_tile(const float* wt, float* dst,
                                           int wave, int lane) {
#pragma unroll
    for (int i = 0; i < 8; ++i) {
        const int inst = wave * 8 + i;
        const int r = inst >> 1;
        const int h = inst & 1;
        const int p = r & 7;
        const float* src = wt + (size_t)r * INF + (h * 64 + (lane ^ p)) * 4;
        gld_lds16(src, dst + inst * 256);
    }
}

// cross-wave K-reduce + store, rounds of 2 groups (fixed order ->
// deterministic). lgkm-only barriers: never drains in-flight staging.
__device__ __forceinline__ void kreduce_store(
        const f32x4* acc, int ng, int s0, int n, int o0,
        int wave, int lane, int mrow, int quad,
        const unsigned short* list, float (*red)[3][4][64],
        float* __restrict__ out) {
#pragma unroll
    for (int r0 = 0; r0 < 4; r0 += 2) {
        if (r0 < ng) {                       // uniform across block
            if (wave != 0) {
#pragma unroll
                for (int g = 0; g < 2; ++g) {
                    if (r0 + g < ng) {
#pragma unroll
                        for (int j = 0; j < 4; ++j)
                            red[g][wave - 1][j][lane] = acc[r0 + g][j];
                    }
                }
            }
            barrier_lgkm();
            if (wave == 0) {
#pragma unroll
                for (int g = 0; g < 2; ++g) {
                    if (r0 + g < ng) {
                        const int s = s0 + (r0 + g) * 16 + mrow;
                        if (s < n) {
                            f32x4 a = acc[r0 + g];
#pragma unroll
                            for (int wv2 = 0; wv2 < 3; ++wv2)
#pragma unroll
                                for (int j = 0; j < 4; ++j)
                                    a[j] += red[g][wv2][j][lane];
                            float* dst = out + (size_t)list[s] * OUTF
                                             + o0 + quad * 4;
                            *(float4*)dst = make_float4(a[0], a[1], a[2], a[3]);
                        }
                    }
                }
            }
            barrier_lgkm();                  // red reusable next round
        }
    }
}

__global__ __launch_bounds__(THREADS, 2)
void switching_linear_kernel(const float* __restrict__ x,
                             const int* __restrict__ idx,
                             const float* __restrict__ w,
                             float* __restrict__ out) {
    __shared__ float Wl[2][OT * INF];       // 64 KB double-buffered W tile
    __shared__ unsigned short list[Bsz];    // 4 KB
    __shared__ int ls_n;
    __shared__ float red[2][3][4][64];      // 6 KB (rounds of 2 groups)

    const int tid  = threadIdx.x;
    const int wave = tid >> 6;
    const int lane = tid & 63;

    // XCD-bijective swizzle: the 8 blocks of a class land on one XCD
    const int bid   = ((int)blockIdx.x & 7) * (NBLK / 8) + ((int)blockIdx.x >> 3);
    const int c     = bid >> 3;                 // class
    const int obase = (bid & 7) * (OT * TPB);   // first of 64 contiguous rows

    if (tid == 0) ls_n = 0;
    __syncthreads();   // nothing in flight yet

    // ---- idx scan + list build ----
    int my[8];
#pragma unroll
    for (int i = 0; i < 8; ++i) my[i] = idx[tid + i * THREADS];
#pragma unroll
    for (int i = 0; i < 8; ++i)
        if (my[i] == c) list[atomicAdd(&ls_n, 1)] = (unsigned short)(tid + i * THREADS);

    __syncthreads();   // list complete (drains idx loads; nothing else)
    const int n = ls_n;
    if (n == 0) return;             // uniform; nothing in flight

    const int mrow = lane & 15;   // A row / C col
    const int quad = lane >> 4;   // k segment / C row group
    const int k0   = wave * (INF / 4);
    const int p    = mrow & 7;
    const float* wc = w + (size_t)c * OUTF * INF + (size_t)obase * INF;

    // ---- prologue ----
    stage_tile(wc, Wl[0], wave, lane);                 // stage(0)

    // x-gather + cvt: its compiler waits drain stage(0) (FIFO) — which
    // tile 0 needed complete anyway. Do NOT issue stage(1) before this.
    const int ng0 = (n >= 64) ? 4 : ((n + 15) >> 4);
    bf16x8 xf[4][4];                // chunk-0 x fragments, reused by all tiles
#pragma unroll
    for (int g = 0; g < 4; ++g) {
        if (g < ng0) {
            const int s  = g * 16 + mrow;
            const int sc = s < n ? s : n - 1;
            const float* bp = x + (size_t)list[sc] * INF + k0 + quad * 8;
#pragma unroll
            for (int i = 0; i < 4; ++i) {
                float4 b0 = *(const float4*)(bp + i * 32);
                float4 b1 = *(const float4*)(bp + i * 32 + 4);
                xf[g][i] = cvt8(b0, b1);
            }
        }
    }

    stage_tile(wc + (size_t)OT * INF, Wl[1], wave, lane);   // stage(1)
    vm8_barrier();   // stage(0) landed block-wide; stage(1) keeps flying

    for (int ot = 0; ot < TPB; ++ot) {
        const float* Wb = Wl[ot & 1];
        const int o0 = obase + ot * OT;

        // A-fragments for this tile (LDS -> regs, lgkm domain only)
        bf16x8 wf[4];
#pragma unroll
        for (int t = 0; t < 4; ++t) {
            const int gb = (k0 >> 2) + t * 8 + quad * 2;   // granule in row
            float4 a0 = *(const float4*)&Wb[mrow * INF + ((gb)     ^ p) * 4];
            float4 a1 = *(const float4*)&Wb[mrow * INF + ((gb + 1) ^ p) * 4];
            wf[t] = cvt8(a0, a1);
        }

        // ---- chunk 0: pure register MFMA (no vmem -> stage stays in flight)
        {
            f32x4 acc[4];
#pragma unroll
            for (int g = 0; g < 4; ++g) acc[g] = (f32x4){0.f, 0.f, 0.f, 0.f};
#pragma unroll
            for (int g = 0; g < 4; ++g) {
                if (g < ng0) {
#pragma unroll
                    for (int i = 0; i < 4; ++i)
                        acc[g] = __builtin_amdgcn_mfma_f32_16x16x32_bf16(
                                     wf[i], xf[g][i], acc[g], 0, 0, 0);
                }
            }
            kreduce_store(acc, ng0, 0, n, o0, wave, lane, mrow, quad,
                          list, red, out);
        }

        // ---- rare slow path: chunks beyond 64 samples (gathers in-loop) ----
        for (int s0 = 64; s0 < n; s0 += 64) {
            const int rem = n - s0;
            const int ng  = rem >= 64 ? 4 : (rem + 15) >> 4;

            f32x4 acc[4];
#pragma unroll
            for (int g = 0; g < 4; ++g) acc[g] = (f32x4){0.f, 0.f, 0.f, 0.f};
#pragma unroll
            for (int g = 0; g < 4; ++g) {
                if (g < ng) {
                    const int s  = s0 + g * 16 + mrow;
                    const int sc = s < n ? s : n - 1;
                    const float* bp = x + (size_t)list[sc] * INF + k0 + quad * 8;
#pragma unroll
                    for (int i = 0; i < 4; ++i) {
                        float4 b0 = *(const float4*)(bp + i * 32);
                        float4 b1 = *(const float4*)(bp + i * 32 + 4);
                        acc[g] = __builtin_amdgcn_mfma_f32_16x16x32_bf16(
                                     wf[i], cvt8(b0, b1), acc[g], 0, 0, 0);
                    }
                }
            }
            kreduce_store(acc, ng, s0, n, o0, wave, lane, mrow, quad,
                          list, red, out);
        }

        // kreduce's final barrier => all waves done reading Wb; B[ot&1] free.
        if (ot + 2 < TPB)
            stage_tile(wc + (size_t)((ot + 2) * OT) * INF, Wl[ot & 1],
                       wave, lane);
        if (ot + 1 < TPB) {
            if (ot + 2 < TPB) vm8_barrier();   // stage(ot+1) landed; (ot+2) flies
            else              vm0_barrier();   // last stage: full drain
        }
    }
}

extern "C" void kernel_launch(void* const* d_in, const int* in_sizes, int n_in,
                              void* d_out, int out_size, void* d_ws, size_t ws_size,
                              hipStream_t stream) {
    const float* x   = (const float*)d_in[0];
    const int*   idx = (const int*)d_in[1];
    const float* w   = (const float*)d_in[2];
    float* out = (float*)d_out;

    switching_linear_kernel<<<dim3(NBLK), dim3(THREADS), 0, stream>>>(x, idx, w, out);
}

// Round 5
// 102.457 us; speedup vs baseline: 1.1331x; 1.0265x over previous
//
#include <hip/hip_runtime.h>

// out[b,o] = sum_k w[idx[b],o,k] * x[b,k];  B=2048, C=64, IN=OUT=512.
//
// r11: r10 (counted vmcnt at tile boundaries) was exactly neutral -> the
// tile-boundary wait IS the BW-limited wait regardless of drain semantics.
// Revised theory: the remaining slack is the PROLOGUE serialization. In
// r9/r10 the x-gathers issue after stage(0); their data-wait (vmcnt FIFO)
// fully drains stage(0) before stage(1) issues -> stream ramps with only
// 32KB outstanding and stage(1) starts ~1.5us late. Fix: issue gathers
// FIRST (oldest in FIFO), then stage(0)+stage(1) back-to-back (64KB
// outstanding immediately), then vmcnt(16) = "gathers landed, stages
// flying", cvt xf under stage flight, vm8_barrier = "stage(0) landed,
// stage(1) flying". sched_barrier(0) pins issue order. Raw data for <=2
// groups (common case, n<=32 typ.) held in 64 VGPRs across stage issues;
// rare ng0>2 groups gathered after (drains stages; P~0.4%).
// Rest = r10: grid 512 (64 classes x 8 row-groups), contiguous 128KB W
// stream/block, 2x32KB Wl double buffer, source-side 16B-granule XOR
// swizzle, XCD-bijective block swizzle, counted vm8 tile barriers,
// lgkm-only reduce barriers, LDS 75.8KB -> 2 blocks/CU.

constexpr int Bsz  = 2048;
constexpr int Ccnt = 64;
constexpr int INF  = 512;
constexpr int OUTF = 512;
constexpr int THREADS = 256;   // 4 waves = 4 K-quarters
constexpr int OT  = 16;        // out rows per staged tile
constexpr int TPB = 4;         // consecutive tiles per block
constexpr int NBLK = Ccnt * (OUTF / (OT * TPB));   // 512

typedef __attribute__((ext_vector_type(8))) short bf16x8;
typedef __attribute__((ext_vector_type(4))) float f32x4;

#if __has_builtin(__builtin_amdgcn_cvt_pk_bf16_f32)
typedef __attribute__((ext_vector_type(2))) __bf16 bf16x2_t;
__device__ __forceinline__ int cvt2i(float a, float b) {
    union { bf16x2_t v; int i; } u;
    u.v = __builtin_amdgcn_cvt_pk_bf16_f32(a, b);
    return u.i;
}
#else
__device__ __forceinline__ unsigned f2bf(float f) {
    union { float f; unsigned u; } v; v.f = f;
    return (v.u + 0x7FFFu + ((v.u >> 16) & 1u)) >> 16;   // RNE
}
__device__ __forceinline__ int cvt2i(float a, float b) {
    return (int)(f2bf(a) | (f2bf(b) << 16));
}
#endif

__device__ __forceinline__ bf16x8 cvt8(float4 a, float4 b) {
    union { bf16x8 v; int i[4]; } u;
    u.i[0] = cvt2i(a.x, a.y);
    u.i[1] = cvt2i(a.z, a.w);
    u.i[2] = cvt2i(b.x, b.y);
    u.i[3] = cvt2i(b.z, b.w);
    return u.v;
}

// async 16B/lane global -> LDS (dest = wave-uniform base + lane*16)
__device__ __forceinline__ void gld_lds16(const float* g, float* l) {
    __builtin_amdgcn_global_load_lds(
        (const __attribute__((address_space(1))) float*)g,
        (__attribute__((address_space(3))) float*)l, 16, 0, 0);
}

// workgroup barrier that does NOT touch vmcnt (keeps staging in flight)
__device__ __forceinline__ void barrier_lgkm() {
    asm volatile("s_waitcnt lgkmcnt(0)" ::: "memory");
    __builtin_amdgcn_s_barrier();
    asm volatile("" ::: "memory");
}

// counted-vmcnt barriers: own stage portion (8 ops) landed, next keeps flying
__device__ __forceinline__ void vm8_barrier() {
    asm volatile("s_waitcnt vmcnt(8)" ::: "memory");
    __builtin_amdgcn_sched_barrier(0);
    __builtin_amdgcn_s_barrier();
    asm volatile("" ::: "memory");
}
__device__ __forceinline__ void vm0_barrier() {
    asm volatile("s_waitcnt vmcnt(0)" ::: "memory");
    __builtin_amdgcn_sched_barrier(0);
    __builtin_amdgcn_s_barrier();
    asm volatile("" ::: "memory");
}

// stage one 16x512 f32 tile (contiguous 32KB) into LDS, 8 x 1KB insts/wave.
// Element (r,k) lands at dst[r*512 + (((k>>2) ^ (r&7)))*4 + (k&3)] (16B-
// granule XOR swizzle applied on the SOURCE side within 128B lines ->
// coalescing identical to a linear copy; reads de-swizzle with same XOR).
__device__ __forceinline__ void stage_tile(const float* wt, float* dst,
                                           int wave, int lane) {
#pragma unroll
    for (int i = 0; i < 8; ++i) {
        const int inst = wave * 8 + i;
        const int r = inst >> 1;
        const int h = inst & 1;
        const int p = r & 7;
        const float* src = wt + (size_t)r * INF + (h * 64 + (lane ^ p)) * 4;
        gld_lds16(src, dst + inst * 256);
    }
}

// cross-wave K-reduce + store, rounds of 2 groups (fixed order ->
// deterministic). lgkm-only barriers: never drains in-flight staging.
__device__ __forceinline__ void kreduce_store(
        const f32x4* acc, int ng, int s0, int n, int o0,
        int wave, int lane, int mrow, int quad,
        const unsigned short* list, float (*red)[3][4][64],
        float* __restrict__ out) {
#pragma unroll
    for (int r0 = 0; r0 < 4; r0 += 2) {
        if (r0 < ng) {                       // uniform across block
            if (wave != 0) {
#pragma unroll
                for (int g = 0; g < 2; ++g) {
                    if (r0 + g < ng) {
#pragma unroll
                        for (int j = 0; j < 4; ++j)
                            red[g][wave - 1][j][lane] = acc[r0 + g][j];
                    }
                }
            }
            barrier_lgkm();
            if (wave == 0) {
#pragma unroll
                for (int g = 0; g < 2; ++g) {
                    if (r0 + g < ng) {
                        const int s = s0 + (r0 + g) * 16 + mrow;
                        if (s < n) {
                            f32x4 a = acc[r0 + g];
#pragma unroll
                            for (int wv2 = 0; wv2 < 3; ++wv2)
#pragma unroll
                                for (int j = 0; j < 4; ++j)
                                    a[j] += red[g][wv2][j][lane];
                            float* dst = out + (size_t)list[s] * OUTF
                                             + o0 + quad * 4;
                            *(float4*)dst = make_float4(a[0], a[1], a[2], a[3]);
                        }
                    }
                }
            }
            barrier_lgkm();                  // red reusable next round
        }
    }
}

__global__ __launch_bounds__(THREADS, 2)
void switching_linear_kernel(const float* __restrict__ x,
                             const int* __restrict__ idx,
                             const float* __restrict__ w,
                             float* __restrict__ out) {
    __shared__ float Wl[2][OT * INF];       // 64 KB double-buffered W tile
    __shared__ unsigned short list[Bsz];    // 4 KB
    __shared__ int ls_n;
    __shared__ float red[2][3][4][64];      // 6 KB (rounds of 2 groups)

    const int tid  = threadIdx.x;
    const int wave = tid >> 6;
    const int lane = tid & 63;

    // XCD-bijective swizzle: the 8 blocks of a class land on one XCD
    const int bid   = ((int)blockIdx.x & 7) * (NBLK / 8) + ((int)blockIdx.x >> 3);
    const int c     = bid >> 3;                 // class
    const int obase = (bid & 7) * (OT * TPB);   // first of 64 contiguous rows

    if (tid == 0) ls_n = 0;
    __syncthreads();   // nothing in flight yet

    // ---- idx scan + list build ----
    int my[8];
#pragma unroll
    for (int i = 0; i < 8; ++i) my[i] = idx[tid + i * THREADS];
#pragma unroll
    for (int i = 0; i < 8; ++i)
        if (my[i] == c) list[atomicAdd(&ls_n, 1)] = (unsigned short)(tid + i * THREADS);

    __syncthreads();   // list complete (drains idx loads; nothing else)
    const int n = ls_n;
    if (n == 0) return;             // uniform; nothing in flight

    const int mrow = lane & 15;   // A row / C col
    const int quad = lane >> 4;   // k segment / C row group
    const int k0   = wave * (INF / 4);
    const int p    = mrow & 7;
    const float* wc = w + (size_t)c * OUTF * INF + (size_t)obase * INF;

    const int ng0 = (n >= 64) ? 4 : ((n + 15) >> 4);
    const int ngp = ng0 < 2 ? ng0 : 2;   // groups preloaded before staging

    // ---- prologue: gathers FIRST (oldest in FIFO), then both stages ----
    float4 raw[2][8];               // ngp groups of raw x data (<=64 VGPR)
#pragma unroll
    for (int g = 0; g < 2; ++g) {
        if (g < ngp) {              // block-uniform -> per-wave count uniform
            const int s  = g * 16 + mrow;
            const int sc = s < n ? s : n - 1;
            const float* bp = x + (size_t)list[sc] * INF + k0 + quad * 8;
#pragma unroll
            for (int i = 0; i < 4; ++i) {
                raw[g][2 * i]     = *(const float4*)(bp + i * 32);
                raw[g][2 * i + 1] = *(const float4*)(bp + i * 32 + 4);
            }
        }
    }
    __builtin_amdgcn_sched_barrier(0);   // pin: gathers precede stage issues

    stage_tile(wc, Wl[0], wave, lane);                      // stage(0)
    stage_tile(wc + (size_t)OT * INF, Wl[1], wave, lane);   // stage(1)

    asm volatile("s_waitcnt vmcnt(16)" ::: "memory");  // gathers landed;
    __builtin_amdgcn_sched_barrier(0);                 // both stages flying

    bf16x8 xf[4][4];                // chunk-0 x fragments, reused by all tiles
#pragma unroll
    for (int g = 0; g < 2; ++g) {
        if (g < ngp) {
#pragma unroll
            for (int i = 0; i < 4; ++i)
                xf[g][i] = cvt8(raw[g][2 * i], raw[g][2 * i + 1]);
        }
    }
    if (ng0 > 2) {   // rare (n>32): gather remaining groups; compiler waits
#pragma unroll       // drain the stages (acceptable on this path)
        for (int g = 2; g < 4; ++g) {
            if (g < ng0) {
                const int s  = g * 16 + mrow;
                const int sc = s < n ? s : n - 1;
                const float* bp = x + (size_t)list[sc] * INF + k0 + quad * 8;
#pragma unroll
                for (int i = 0; i < 4; ++i) {
                    float4 b0 = *(const float4*)(bp + i * 32);
                    float4 b1 = *(const float4*)(bp + i * 32 + 4);
                    xf[g][i] = cvt8(b0, b1);
                }
            }
        }
    }

    vm8_barrier();   // stage(0) landed block-wide; stage(1) keeps flying

    for (int ot = 0; ot < TPB; ++ot) {
        const float* Wb = Wl[ot & 1];
        const int o0 = obase + ot * OT;

        // A-fragments for this tile (LDS -> regs, lgkm domain only)
        bf16x8 wf[4];
#pragma unroll
        for (int t = 0; t < 4; ++t) {
            const int gb = (k0 >> 2) + t * 8 + quad * 2;   // granule in row
            float4 a0 = *(const float4*)&Wb[mrow * INF + ((gb)     ^ p) * 4];
            float4 a1 = *(const float4*)&Wb[mrow * INF + ((gb + 1) ^ p) * 4];
            wf[t] = cvt8(a0, a1);
        }

        // ---- chunk 0: pure register MFMA (no vmem -> stage stays in flight)
        {
            f32x4 acc[4];
#pragma unroll
            for (int g = 0; g < 4; ++g) acc[g] = (f32x4){0.f, 0.f, 0.f, 0.f};
#pragma unroll
            for (int g = 0; g < 4; ++g) {
                if (g < ng0) {
#pragma unroll
                    for (int i = 0; i < 4; ++i)
                        acc[g] = __builtin_amdgcn_mfma_f32_16x16x32_bf16(
                                     wf[i], xf[g][i], acc[g], 0, 0, 0);
                }
            }
            kreduce_store(acc, ng0, 0, n, o0, wave, lane, mrow, quad,
                          list, red, out);
        }

        // ---- rare slow path: chunks beyond 64 samples (gathers in-loop) ----
        for (int s0 = 64; s0 < n; s0 += 64) {
            const int rem = n - s0;
            const int ng  = rem >= 64 ? 4 : (rem + 15) >> 4;

            f32x4 acc[4];
#pragma unroll
            for (int g = 0; g < 4; ++g) acc[g] = (f32x4){0.f, 0.f, 0.f, 0.f};
#pragma unroll
            for (int g = 0; g < 4; ++g) {
                if (g < ng) {
                    const int s  = s0 + g * 16 + mrow;
                    const int sc = s < n ? s : n - 1;
                    const float* bp = x + (size_t)list[sc] * INF + k0 + quad * 8;
#pragma unroll
                    for (int i = 0; i < 4; ++i) {
                        float4 b0 = *(const float4*)(bp + i * 32);
                        float4 b1 = *(const float4*)(bp + i * 32 + 4);
                        acc[g] = __builtin_amdgcn_mfma_f32_16x16x32_bf16(
                                     wf[i], cvt8(b0, b1), acc[g], 0, 0, 0);
                    }
                }
            }
            kreduce_store(acc, ng, s0, n, o0, wave, lane, mrow, quad,
                          list, red, out);
        }

        // kreduce's final barrier => all waves done reading Wb; B[ot&1] free.
        if (ot + 2 < TPB)
            stage_tile(wc + (size_t)((ot + 2) * OT) * INF, Wl[ot & 1],
                       wave, lane);
        if (ot + 1 < TPB) {
            if (ot + 2 < TPB) vm8_barrier();   // stage(ot+1) landed; (ot+2) flies
            else              vm0_barrier();   // last stage: full drain
        }
    }
}

extern "C" void kernel_launch(void* const* d_in, const int* in_sizes, int n_in,
                              void* d_out, int out_size, void* d_ws, size_t ws_size,
                              hipStream_t stream) {
    const float* x   = (const float*)d_in[0];
    const int*   idx = (const int*)d_in[1];
    const float* w   = (const float*)d_in[2];
    float* out = (float*)d_out;

    switching_linear_kernel<<<dim3(NBLK), dim3(THREADS), 0, stream>>>(x, idx, w, out);
}